// Round 8
// baseline (270.350 us; speedup 1.0000x reference)
//
#include <hip/hip_runtime.h>

#define N_NODES 50000
#define N_EDGES 600000
#define D 128
#define CAP 64   // fixed-capacity neighbor rows; P(deg>64) ~ 1e-26 here; spill path keeps correctness for any input
#define NTILES (N_NODES / 16)   // 3125
#define PERSIST_BLOCKS 2048     // = 256 CU x 8 blocks/CU residency capacity (VGPR48/LDS4.6KB allow 8)

typedef __attribute__((ext_vector_type(8))) short bf16x8;
typedef __attribute__((ext_vector_type(4))) float floatx4;

__device__ inline unsigned int f2bf(float f) {
    unsigned int u = __float_as_uint(f);
    return (u + 0x7FFFu + ((u >> 16) & 1u)) >> 16;   // RNE
}
__device__ inline float bf_lo(unsigned int u) { return __uint_as_float(u << 16); }
__device__ inline float bf_hi(unsigned int u) { return __uint_as_float(u & 0xFFFF0000u); }

// ---------------- fused prep: edge bucketing + cvt x -> bf16 + cvt W -> bf16 ----
// blocks [0,586): edge bucketing, 4 edges/thread via int4 loads
// blocks [586,6836): x conversion (1 float4/thread) -> xbf (lives in d_out)
// blocks [6836,7092): weight conversion (4 * 128*128 elems)
__global__ void k_prep(const float* __restrict__ x, unsigned short* __restrict__ xbf,
                       const float* __restrict__ wa, const float* __restrict__ wb,
                       const float* __restrict__ wc, const float* __restrict__ wd,
                       unsigned short* __restrict__ wbf,
                       const int* __restrict__ src, const int* __restrict__ dst,
                       int* __restrict__ cnt, unsigned short* __restrict__ buf,
                       int* __restrict__ spillN, int* __restrict__ spillD,
                       int* __restrict__ spillS) {
    const int b = blockIdx.x;
    const int t = threadIdx.x;
    if (b < 586) {
        int idx = b * 256 + t;                 // quad-edge index
        if (idx * 4 < N_EDGES) {               // N_EDGES % 4 == 0 -> full int4 always
            int4 dv = ((const int4*)dst)[idx];
            int4 sv = ((const int4*)src)[idx];
            int p0 = atomicAdd(&cnt[dv.x], 1);
            int p1 = atomicAdd(&cnt[dv.y], 1);
            int p2 = atomicAdd(&cnt[dv.z], 1);
            int p3 = atomicAdd(&cnt[dv.w], 1);
            if (p0 < CAP) buf[(size_t)dv.x * CAP + p0] = (unsigned short)sv.x;
            else { int k = atomicAdd(spillN, 1); spillD[k] = dv.x; spillS[k] = sv.x; }
            if (p1 < CAP) buf[(size_t)dv.y * CAP + p1] = (unsigned short)sv.y;
            else { int k = atomicAdd(spillN, 1); spillD[k] = dv.y; spillS[k] = sv.y; }
            if (p2 < CAP) buf[(size_t)dv.z * CAP + p2] = (unsigned short)sv.z;
            else { int k = atomicAdd(spillN, 1); spillD[k] = dv.z; spillS[k] = sv.z; }
            if (p3 < CAP) buf[(size_t)dv.w * CAP + p3] = (unsigned short)sv.w;
            else { int k = atomicAdd(spillN, 1); spillD[k] = dv.w; spillS[k] = sv.w; }
        }
    } else if (b < 6836) {
        int i = (b - 586) * 256 + t;
        float4 v = ((const float4*)x)[i];
        uint2 o;
        o.x = f2bf(v.x) | (f2bf(v.y) << 16);
        o.y = f2bf(v.z) | (f2bf(v.w) << 16);
        ((uint2*)xbf)[i] = o;
    } else {
        int i = (b - 6836) * 256 + t;
        const float* srcs[4] = {wa, wb, wc, wd};
        wbf[i] = (unsigned short)f2bf(srcs[i >> 14][i & 16383]);
    }
}

// ---------------- fused gather + MFMA layer (compute path verbatim R2/R7) ----
// PERSISTENT blocks + dynamic work-stealing: each block pops tile ids from a
// global counter (zeroed by the host memset). Kills the 1.5-round drain tail
// that held OccupancyPercent at ~40% with the static 3125-block grid.
// Per tile (16 nodes):
// Phase 1 (gather): thread (nl=t>>4, q=t&15) accumulates mean of node node0+nl,
//   cols [8q, 8q+8); 16 consecutive lanes/node -> coalesced 256 B row reads;
//   8-deep unroll. Result -> bf16 LDS tile.
// Phase 2 (MFMA): wave wv computes feats [32wv, 32wv+32) for the 16 nodes.
//   A: lane=(l15,quad) -> row l15, k = quad*8 + kk*32 ; C/D: col=l15, row=quad*4+r.
#define ACC8(vv) do { \
    acc[0] += bf_lo((vv).x); acc[1] += bf_hi((vv).x); \
    acc[2] += bf_lo((vv).y); acc[3] += bf_hi((vv).y); \
    acc[4] += bf_lo((vv).z); acc[5] += bf_hi((vv).z); \
    acc[6] += bf_lo((vv).w); acc[7] += bf_hi((vv).w); } while (0)

template <bool RELU, bool OUT_BF16>
__global__ void __launch_bounds__(256) k_gather_layer(
    int* __restrict__ tileCtr,
    const int* __restrict__ cnt, const unsigned short* __restrict__ buf,
    const int* __restrict__ spillN, const int* __restrict__ spillD,
    const int* __restrict__ spillS,
    const unsigned short* __restrict__ Xbf,
    const unsigned short* __restrict__ Wlbf, const float* __restrict__ bias,
    const unsigned short* __restrict__ Wrbf, void* __restrict__ outp) {
    __shared__ unsigned short tile[16][136];   // 272 B row stride (16B-mult)
    __shared__ int s_tile;

    const int t = threadIdx.x;

    for (;;) {
        if (t == 0) s_tile = atomicAdd(tileCtr, 1);
        __syncthreads();
        const int tl = s_tile;
        if (tl >= NTILES) return;              // uniform exit
        const int node0 = tl * 16;

        // ---- phase 1: gather mean ----
        {
            const int nl = t >> 4, q = t & 15;
            const int node = node0 + nl;
            const int deg = cnt[node];
            const int m = deg < CAP ? deg : CAP;
            const unsigned short* __restrict__ nb = buf + (size_t)node * CAP;
            float acc[8] = {0.f, 0.f, 0.f, 0.f, 0.f, 0.f, 0.f, 0.f};
            int e = 0;
            for (; e + 8 <= m; e += 8) {
                uint4 v[8];
#pragma unroll
                for (int u = 0; u < 8; ++u)
                    v[u] = *(const uint4*)(Xbf + (size_t)nb[e + u] * D + q * 8);
#pragma unroll
                for (int u = 0; u < 8; ++u) ACC8(v[u]);
            }
            for (; e + 4 <= m; e += 4) {
                uint4 v[4];
#pragma unroll
                for (int u = 0; u < 4; ++u)
                    v[u] = *(const uint4*)(Xbf + (size_t)nb[e + u] * D + q * 8);
#pragma unroll
                for (int u = 0; u < 4; ++u) ACC8(v[u]);
            }
            for (; e < m; ++e) {
                uint4 v = *(const uint4*)(Xbf + (size_t)nb[e] * D + q * 8);
                ACC8(v);
            }
            if (deg > CAP) {                   // correctness-only path; never taken for this graph
                int sn = *spillN;
                for (int k = 0; k < sn; ++k) {
                    if (spillD[k] == node) {
                        uint4 v = *(const uint4*)(Xbf + (size_t)spillS[k] * D + q * 8);
                        ACC8(v);
                    }
                }
            }
            float inv = (deg > 0) ? 1.0f / (float)deg : 0.0f;
            uint4 o;
            o.x = f2bf(acc[0] * inv) | (f2bf(acc[1] * inv) << 16);
            o.y = f2bf(acc[2] * inv) | (f2bf(acc[3] * inv) << 16);
            o.z = f2bf(acc[4] * inv) | (f2bf(acc[5] * inv) << 16);
            o.w = f2bf(acc[6] * inv) | (f2bf(acc[7] * inv) << 16);
            *(uint4*)(&tile[nl][q * 8]) = o;
        }
        __syncthreads();

        // ---- phase 2: MFMA ----
        {
            const int lane = t & 63;
            const int wv = t >> 6;             // wave id 0..3 -> feats [32wv, 32wv+32)
            const int l15 = lane & 15;
            const int quad = lane >> 4;

            floatx4 c0 = (floatx4)(0.f), c1 = (floatx4)(0.f);
            const int nf0 = wv * 2, nf1 = wv * 2 + 1;

            const unsigned short* mrow = &tile[l15][quad * 8];
            const unsigned short* arowX = Xbf + (size_t)(node0 + l15) * D + quad * 8;

#pragma unroll
            for (int kk = 0; kk < 4; ++kk) {
                bf16x8 a = *(const bf16x8*)(mrow + kk * 32);
                bf16x8 b0 = *(const bf16x8*)(Wlbf + (size_t)(nf0 * 16 + l15) * D + kk * 32 + quad * 8);
                bf16x8 b1 = *(const bf16x8*)(Wlbf + (size_t)(nf1 * 16 + l15) * D + kk * 32 + quad * 8);
                c0 = __builtin_amdgcn_mfma_f32_16x16x32_bf16(a, b0, c0, 0, 0, 0);
                c1 = __builtin_amdgcn_mfma_f32_16x16x32_bf16(a, b1, c1, 0, 0, 0);
            }
#pragma unroll
            for (int kk = 0; kk < 4; ++kk) {
                bf16x8 a = *(const bf16x8*)(arowX + kk * 32);
                bf16x8 b0 = *(const bf16x8*)(Wrbf + (size_t)(nf0 * 16 + l15) * D + kk * 32 + quad * 8);
                bf16x8 b1 = *(const bf16x8*)(Wrbf + (size_t)(nf1 * 16 + l15) * D + kk * 32 + quad * 8);
                c0 = __builtin_amdgcn_mfma_f32_16x16x32_bf16(a, b0, c0, 0, 0, 0);
                c1 = __builtin_amdgcn_mfma_f32_16x16x32_bf16(a, b1, c1, 0, 0, 0);
            }

#pragma unroll
            for (int j = 0; j < 2; ++j) {
                floatx4 c = j ? c1 : c0;
                int f = (wv * 2 + j) * 16 + l15;
                float bv = bias[f];
#pragma unroll
                for (int r = 0; r < 4; ++r) {
                    float v = c[r] + bv;
                    if (RELU) v = v > 0.f ? v : 0.2f * v;
                    int node = node0 + quad * 4 + r;
                    if (OUT_BF16)
                        ((unsigned short*)outp)[(size_t)node * D + f] = (unsigned short)f2bf(v);
                    else
                        ((float*)outp)[(size_t)node * D + f] = v;
                }
            }
        }
        __syncthreads();   // tile LDS + s_tile reused by next iteration
    }
}

// ---------------- host launch ----------------

extern "C" void kernel_launch(void* const* d_in, const int* in_sizes, int n_in,
                              void* d_out, int out_size, void* d_ws, size_t ws_size,
                              hipStream_t stream) {
    (void)in_sizes; (void)n_in; (void)out_size; (void)ws_size;

    const float* x   = (const float*)d_in[0];
    const int*   ei  = (const int*)d_in[1];
    const float* W1l = (const float*)d_in[2];
    const float* b1  = (const float*)d_in[3];
    const float* W1r = (const float*)d_in[4];
    const float* W2l = (const float*)d_in[5];
    const float* b2  = (const float*)d_in[6];
    const float* W2r = (const float*)d_in[7];

    const int* src = ei;
    const int* dst = ei + N_EDGES;

    char* ws = (char*)d_ws;
    int* cnt              = (int*)(ws + 0);                  // 200,000 B
    int* spillN           = (int*)(ws + 200000);             // 4 B
    int* tileCtr1         = (int*)(ws + 200008);             // 4 B  (inside memset range)
    int* tileCtr2         = (int*)(ws + 200012);             // 4 B  (inside memset range)
    int* spillD           = (int*)(ws + 200064);             // 2,400,000 B
    int* spillS           = (int*)(ws + 2600064);            // 2,400,000 B
    unsigned short* buf   = (unsigned short*)(ws + 5000064); // 6,400,000 B (50000*64 u16)
    unsigned short* wbf   = (unsigned short*)(ws + 11400064);// 131,072 B
    unsigned short* hbf   = (unsigned short*)(ws + 11531136);// 12,800,000 B  (ends 24.3 MB)

    // xbf lives in d_out (25.6 MB): layer 2 never reads x, so the final fp32
    // output write may clobber it.
    unsigned short* xbf = (unsigned short*)d_out;
    float* out = (float*)d_out;

    unsigned short* w1l_bf = wbf;
    unsigned short* w1r_bf = wbf + 16384;
    unsigned short* w2l_bf = wbf + 32768;
    unsigned short* w2r_bf = wbf + 49152;

    hipMemsetAsync(ws, 0, 200064, stream);   // cnt + spillN + tile counters

    k_prep<<<7092, 256, 0, stream>>>(x, xbf, W1l, W1r, W2l, W2r, wbf,
                                     src, dst, cnt, buf, spillN, spillD, spillS);

    k_gather_layer<true, true><<<PERSIST_BLOCKS, 256, 0, stream>>>(
        tileCtr1, cnt, buf, spillN, spillD, spillS, xbf, w1l_bf, b1, w1r_bf, (void*)hbf);
    k_gather_layer<false, false><<<PERSIST_BLOCKS, 256, 0, stream>>>(
        tileCtr2, cnt, buf, spillN, spillD, spillS, hbf, w2l_bf, b2, w2r_bf, (void*)out);
}

// Round 10
// 219.075 us; speedup vs baseline: 1.2341x; 1.2341x over previous
//
#include <hip/hip_runtime.h>

#define N_NODES 50000
#define N_EDGES 600000
#define D 128
#define CAP 64   // fixed-capacity neighbor rows; P(deg>64) ~ 1e-26 here; spill path keeps correctness for any input
#define NTILES (N_NODES / 16)   // 3125

typedef __attribute__((ext_vector_type(8))) short bf16x8;
typedef __attribute__((ext_vector_type(4))) float floatx4;
typedef __attribute__((ext_vector_type(2))) float f32x2;

__device__ inline unsigned int f2bf(float f) {
    unsigned int u = __float_as_uint(f);
    return (u + 0x7FFFu + ((u >> 16) & 1u)) >> 16;   // RNE
}
__device__ inline float bf_lo(unsigned int u) { return __uint_as_float(u << 16); }
__device__ inline float bf_hi(unsigned int u) { return __uint_as_float(u & 0xFFFF0000u); }

// ---------------- fused prep: edge bucketing + cvt x -> bf16 + cvt W -> bf16 ----
// blocks [0,586): edge bucketing, 4 edges/thread via int4 loads
// blocks [586,6836): x conversion (1 float4/thread) -> xbf (lives in d_out)
// blocks [6836,7092): weight conversion (4 * 128*128 elems)
__global__ void k_prep(const float* __restrict__ x, unsigned short* __restrict__ xbf,
                       const float* __restrict__ wa, const float* __restrict__ wb,
                       const float* __restrict__ wc, const float* __restrict__ wd,
                       unsigned short* __restrict__ wbf,
                       const int* __restrict__ src, const int* __restrict__ dst,
                       int* __restrict__ cnt, unsigned short* __restrict__ buf,
                       int* __restrict__ spillN, unsigned int* __restrict__ spillP) {
    const int b = blockIdx.x;
    const int t = threadIdx.x;
    if (b < 586) {
        int idx = b * 256 + t;                 // quad-edge index
        if (idx * 4 < N_EDGES) {               // N_EDGES % 4 == 0 -> full int4 always
            int4 dv = ((const int4*)dst)[idx];
            int4 sv = ((const int4*)src)[idx];
            int p0 = atomicAdd(&cnt[dv.x], 1);
            int p1 = atomicAdd(&cnt[dv.y], 1);
            int p2 = atomicAdd(&cnt[dv.z], 1);
            int p3 = atomicAdd(&cnt[dv.w], 1);
            if (p0 < CAP) buf[(size_t)dv.x * CAP + p0] = (unsigned short)sv.x;
            else { int k = atomicAdd(spillN, 1); spillP[k] = ((unsigned)dv.x << 16) | (unsigned)sv.x; }
            if (p1 < CAP) buf[(size_t)dv.y * CAP + p1] = (unsigned short)sv.y;
            else { int k = atomicAdd(spillN, 1); spillP[k] = ((unsigned)dv.y << 16) | (unsigned)sv.y; }
            if (p2 < CAP) buf[(size_t)dv.z * CAP + p2] = (unsigned short)sv.z;
            else { int k = atomicAdd(spillN, 1); spillP[k] = ((unsigned)dv.z << 16) | (unsigned)sv.z; }
            if (p3 < CAP) buf[(size_t)dv.w * CAP + p3] = (unsigned short)sv.w;
            else { int k = atomicAdd(spillN, 1); spillP[k] = ((unsigned)dv.w << 16) | (unsigned)sv.w; }
        }
    } else if (b < 6836) {
        int i = (b - 586) * 256 + t;
        float4 v = ((const float4*)x)[i];
        uint2 o;
        o.x = f2bf(v.x) | (f2bf(v.y) << 16);
        o.y = f2bf(v.z) | (f2bf(v.w) << 16);
        ((uint2*)xbf)[i] = o;
    } else {
        int i = (b - 6836) * 256 + t;
        const float* srcs[4] = {wa, wb, wc, wd};
        wbf[i] = (unsigned short)f2bf(srcs[i >> 14][i & 16383]);
    }
}

// ---------------- fused gather + MFMA layer ----------------
// Block = 256 threads = 16 nodes (static grid 3125 — best proven schedule).
// Phase 1 (gather): thread (nl=t>>4, q=t&15) accumulates mean of node node0+nl,
//   cols [8q, 8q+8) in fp32. GATHER_FP8=false: bf16 rows, 256B/row (R7-proven).
//   GATHER_FP8=true: fp8 rows, 128B/row = 2 cache lines instead of 4 (traffic
//   lever), HW decode via v_cvt_pk_f32_fp8. 8-deep unroll -> bf16 LDS tile.
// Phase 2 (MFMA): unchanged R2-proven path; own-row A and W operands bf16.
//   A: lane=(l15,quad) -> row l15, k = quad*8 + kk*32 ; C/D: col=l15, row=quad*4+r.
#define ACC8(vv) do { \
    acc[0] += bf_lo((vv).x); acc[1] += bf_hi((vv).x); \
    acc[2] += bf_lo((vv).y); acc[3] += bf_hi((vv).y); \
    acc[4] += bf_lo((vv).z); acc[5] += bf_hi((vv).z); \
    acc[6] += bf_lo((vv).w); acc[7] += bf_hi((vv).w); } while (0)

#define ACCF8(vv) do { \
    f32x2 p0 = __builtin_amdgcn_cvt_pk_f32_fp8((vv).x, false); \
    f32x2 p1 = __builtin_amdgcn_cvt_pk_f32_fp8((vv).x, true);  \
    f32x2 p2 = __builtin_amdgcn_cvt_pk_f32_fp8((vv).y, false); \
    f32x2 p3 = __builtin_amdgcn_cvt_pk_f32_fp8((vv).y, true);  \
    acc[0] += p0.x; acc[1] += p0.y; acc[2] += p1.x; acc[3] += p1.y; \
    acc[4] += p2.x; acc[5] += p2.y; acc[6] += p3.x; acc[7] += p3.y; } while (0)

template <bool RELU, bool OUT_BF16, bool WRITE_FP8, bool GATHER_FP8>
__global__ void __launch_bounds__(256) k_gather_layer(
    const int* __restrict__ cnt, const unsigned short* __restrict__ buf,
    const int* __restrict__ spillN, const unsigned int* __restrict__ spillP,
    const unsigned char* __restrict__ X8,      // fp8 rows (used iff GATHER_FP8)
    const unsigned short* __restrict__ Xbf,    // bf16 rows: gather (iff !GATHER_FP8), own-row A, spill
    const unsigned short* __restrict__ Wlbf, const float* __restrict__ bias,
    const unsigned short* __restrict__ Wrbf, void* __restrict__ outp,
    unsigned char* __restrict__ out8) {
    __shared__ unsigned short tile[16][136];   // 272 B row stride (16B-mult)

    const int t = threadIdx.x;
    const int node0 = blockIdx.x * 16;         // grid 3125 -> exact

    // ---- phase 1: gather mean ----
    {
        const int nl = t >> 4, q = t & 15;
        const int node = node0 + nl;
        const int deg = cnt[node];
        const int m = deg < CAP ? deg : CAP;
        const unsigned short* __restrict__ nb = buf + (size_t)node * CAP;
        float acc[8] = {0.f, 0.f, 0.f, 0.f, 0.f, 0.f, 0.f, 0.f};
        int e = 0;
        if (GATHER_FP8) {
            for (; e + 8 <= m; e += 8) {
                uint2 v[8];
#pragma unroll
                for (int u = 0; u < 8; ++u)
                    v[u] = *(const uint2*)(X8 + (size_t)nb[e + u] * D + q * 8);
#pragma unroll
                for (int u = 0; u < 8; ++u) ACCF8(v[u]);
            }
            for (; e + 4 <= m; e += 4) {
                uint2 v[4];
#pragma unroll
                for (int u = 0; u < 4; ++u)
                    v[u] = *(const uint2*)(X8 + (size_t)nb[e + u] * D + q * 8);
#pragma unroll
                for (int u = 0; u < 4; ++u) ACCF8(v[u]);
            }
            for (; e < m; ++e) {
                uint2 v = *(const uint2*)(X8 + (size_t)nb[e] * D + q * 8);
                ACCF8(v);
            }
        } else {
            for (; e + 8 <= m; e += 8) {
                uint4 v[8];
#pragma unroll
                for (int u = 0; u < 8; ++u)
                    v[u] = *(const uint4*)(Xbf + (size_t)nb[e + u] * D + q * 8);
#pragma unroll
                for (int u = 0; u < 8; ++u) ACC8(v[u]);
            }
            for (; e + 4 <= m; e += 4) {
                uint4 v[4];
#pragma unroll
                for (int u = 0; u < 4; ++u)
                    v[u] = *(const uint4*)(Xbf + (size_t)nb[e + u] * D + q * 8);
#pragma unroll
                for (int u = 0; u < 4; ++u) ACC8(v[u]);
            }
            for (; e < m; ++e) {
                uint4 v = *(const uint4*)(Xbf + (size_t)nb[e] * D + q * 8);
                ACC8(v);
            }
        }
        if (deg > CAP) {                       // correctness-only path (bf16 rows); never taken here
            int sn = *spillN;
            for (int k = 0; k < sn; ++k) {
                unsigned int p = spillP[k];
                if ((int)(p >> 16) == node) {
                    uint4 v = *(const uint4*)(Xbf + (size_t)(p & 0xFFFFu) * D + q * 8);
                    ACC8(v);
                }
            }
        }
        float inv = (deg > 0) ? 1.0f / (float)deg : 0.0f;
        uint4 o;
        o.x = f2bf(acc[0] * inv) | (f2bf(acc[1] * inv) << 16);
        o.y = f2bf(acc[2] * inv) | (f2bf(acc[3] * inv) << 16);
        o.z = f2bf(acc[4] * inv) | (f2bf(acc[5] * inv) << 16);
        o.w = f2bf(acc[6] * inv) | (f2bf(acc[7] * inv) << 16);
        *(uint4*)(&tile[nl][q * 8]) = o;
    }
    __syncthreads();

    // ---- phase 2: MFMA ----
    const int lane = t & 63;
    const int wv = t >> 6;                 // wave id 0..3 -> feats [32wv, 32wv+32)
    const int l15 = lane & 15;
    const int quad = lane >> 4;

    floatx4 c0 = (floatx4)(0.f), c1 = (floatx4)(0.f);
    const int nf0 = wv * 2, nf1 = wv * 2 + 1;

    const unsigned short* mrow = &tile[l15][quad * 8];
    const unsigned short* arowX = Xbf + (size_t)(node0 + l15) * D + quad * 8;

#pragma unroll
    for (int kk = 0; kk < 4; ++kk) {
        bf16x8 a = *(const bf16x8*)(mrow + kk * 32);
        bf16x8 b0 = *(const bf16x8*)(Wlbf + (size_t)(nf0 * 16 + l15) * D + kk * 32 + quad * 8);
        bf16x8 b1 = *(const bf16x8*)(Wlbf + (size_t)(nf1 * 16 + l15) * D + kk * 32 + quad * 8);
        c0 = __builtin_amdgcn_mfma_f32_16x16x32_bf16(a, b0, c0, 0, 0, 0);
        c1 = __builtin_amdgcn_mfma_f32_16x16x32_bf16(a, b1, c1, 0, 0, 0);
    }
#pragma unroll
    for (int kk = 0; kk < 4; ++kk) {
        bf16x8 a = *(const bf16x8*)(arowX + kk * 32);
        bf16x8 b0 = *(const bf16x8*)(Wrbf + (size_t)(nf0 * 16 + l15) * D + kk * 32 + quad * 8);
        bf16x8 b1 = *(const bf16x8*)(Wrbf + (size_t)(nf1 * 16 + l15) * D + kk * 32 + quad * 8);
        c0 = __builtin_amdgcn_mfma_f32_16x16x32_bf16(a, b0, c0, 0, 0, 0);
        c1 = __builtin_amdgcn_mfma_f32_16x16x32_bf16(a, b1, c1, 0, 0, 0);
    }

#pragma unroll
    for (int j = 0; j < 2; ++j) {
        floatx4 c = j ? c1 : c0;
        int f = (wv * 2 + j) * 16 + l15;
        float bv = bias[f];
#pragma unroll
        for (int r = 0; r < 4; ++r) {
            float v = c[r] + bv;
            if (RELU) v = v > 0.f ? v : 0.2f * v;
            int node = node0 + quad * 4 + r;
            if (OUT_BF16)
                ((unsigned short*)outp)[(size_t)node * D + f] = (unsigned short)f2bf(v);
            else
                ((float*)outp)[(size_t)node * D + f] = v;
            if (WRITE_FP8) {
                int pk = __builtin_amdgcn_cvt_pk_fp8_f32(v, v, 0, false);
                out8[(size_t)node * D + f] = (unsigned char)(pk & 0xFF);
            }
        }
    }
}

// ---------------- host launch ----------------

extern "C" void kernel_launch(void* const* d_in, const int* in_sizes, int n_in,
                              void* d_out, int out_size, void* d_ws, size_t ws_size,
                              hipStream_t stream) {
    (void)in_sizes; (void)n_in; (void)out_size; (void)ws_size;

    const float* x   = (const float*)d_in[0];
    const int*   ei  = (const int*)d_in[1];
    const float* W1l = (const float*)d_in[2];
    const float* b1  = (const float*)d_in[3];
    const float* W1r = (const float*)d_in[4];
    const float* W2l = (const float*)d_in[5];
    const float* b2  = (const float*)d_in[6];
    const float* W2r = (const float*)d_in[7];

    const int* src = ei;
    const int* dst = ei + N_EDGES;

    char* ws = (char*)d_ws;
    int* cnt              = (int*)(ws + 0);                      // 200,000 B
    int* spillN           = (int*)(ws + 200000);                 // 4 B (zeroed with cnt)
    unsigned int* spillP  = (unsigned int*)(ws + 200064);        // 2,400,000 B packed (dst<<16|src)
    unsigned short* buf   = (unsigned short*)(ws + 2600064);     // 6,400,000 B (50000*64 u16)
    unsigned short* wbf   = (unsigned short*)(ws + 9000064);     // 131,072 B
    unsigned short* hbf   = (unsigned short*)(ws + 9131136);     // 12,800,000 B
    unsigned char* h8     = (unsigned char*)(ws + 21931136);     // 6,400,000 B  (ends 28.33 MB <= proven 28.73 MB)

    // d_out (25.6 MB) holds ONLY xbf (R7-proven pattern): layer 2 never reads x,
    // so the final fp32 output write may clobber it.
    unsigned short* xbf = (unsigned short*)d_out;
    float* out = (float*)d_out;

    unsigned short* w1l_bf = wbf;
    unsigned short* w1r_bf = wbf + 16384;
    unsigned short* w2l_bf = wbf + 32768;
    unsigned short* w2r_bf = wbf + 49152;

    hipMemsetAsync(ws, 0, 200064, stream);   // cnt + spillN

    k_prep<<<7092, 256, 0, stream>>>(x, xbf, W1l, W1r, W2l, W2r, wbf,
                                     src, dst, cnt, buf, spillN, spillP);

    // layer 1: bf16 gather from xbf (R7-proven), writes hbf (bf16) + h8 (fp8)
    k_gather_layer<true, true, true, false><<<NTILES, 256, 0, stream>>>(
        cnt, buf, spillN, spillP, nullptr, xbf, w1l_bf, b1, w1r_bf, (void*)hbf, h8);
    // layer 2: fp8 gather from h8 (2 lines/row instead of 4), bf16 own-row/W
    k_gather_layer<false, false, false, true><<<NTILES, 256, 0, stream>>>(
        cnt, buf, spillN, spillP, h8, hbf, w2l_bf, b2, w2r_bf, (void*)out, nullptr);
}

// Round 11
// 217.055 us; speedup vs baseline: 1.2455x; 1.0093x over previous
//
#include <hip/hip_runtime.h>

#define N_NODES 50000
#define N_EDGES 600000
#define D 128
#define CAP 32   // fixed-capacity neighbor rows. E[max deg] ~ 28 for this graph (Poisson-12, 50K draws);
                 // spill path keeps correctness for ANY input. CAP=32 halves the prep scatter's RFO
                 // working set (6.4 -> 3.2 MB: fits one XCD L2) and the gather's id-line touches.
#define NTILES (N_NODES / 16)   // 3125

typedef __attribute__((ext_vector_type(8))) short bf16x8;
typedef __attribute__((ext_vector_type(4))) float floatx4;
typedef __attribute__((ext_vector_type(2))) float f32x2;

__device__ inline unsigned int f2bf(float f) {
    unsigned int u = __float_as_uint(f);
    return (u + 0x7FFFu + ((u >> 16) & 1u)) >> 16;   // RNE
}
__device__ inline float bf_lo(unsigned int u) { return __uint_as_float(u << 16); }
__device__ inline float bf_hi(unsigned int u) { return __uint_as_float(u & 0xFFFF0000u); }

// ---------------- fused prep: edge bucketing + cvt x -> bf16 + cvt W -> bf16 ----
// blocks [0,586): edge bucketing, 4 edges/thread via int4 loads
// blocks [586,6836): x conversion (1 float4/thread) -> xbf (lives in d_out)
// blocks [6836,7092): weight conversion (4 * 128*128 elems)
__global__ void k_prep(const float* __restrict__ x, unsigned short* __restrict__ xbf,
                       const float* __restrict__ wa, const float* __restrict__ wb,
                       const float* __restrict__ wc, const float* __restrict__ wd,
                       unsigned short* __restrict__ wbf,
                       const int* __restrict__ src, const int* __restrict__ dst,
                       int* __restrict__ cnt, unsigned short* __restrict__ buf,
                       int* __restrict__ spillN, unsigned int* __restrict__ spillP) {
    const int b = blockIdx.x;
    const int t = threadIdx.x;
    if (b < 586) {
        int idx = b * 256 + t;                 // quad-edge index
        if (idx * 4 < N_EDGES) {               // N_EDGES % 4 == 0 -> full int4 always
            int4 dv = ((const int4*)dst)[idx];
            int4 sv = ((const int4*)src)[idx];
            int p0 = atomicAdd(&cnt[dv.x], 1);
            int p1 = atomicAdd(&cnt[dv.y], 1);
            int p2 = atomicAdd(&cnt[dv.z], 1);
            int p3 = atomicAdd(&cnt[dv.w], 1);
            if (p0 < CAP) buf[(size_t)dv.x * CAP + p0] = (unsigned short)sv.x;
            else { int k = atomicAdd(spillN, 1); spillP[k] = ((unsigned)dv.x << 16) | (unsigned)sv.x; }
            if (p1 < CAP) buf[(size_t)dv.y * CAP + p1] = (unsigned short)sv.y;
            else { int k = atomicAdd(spillN, 1); spillP[k] = ((unsigned)dv.y << 16) | (unsigned)sv.y; }
            if (p2 < CAP) buf[(size_t)dv.z * CAP + p2] = (unsigned short)sv.z;
            else { int k = atomicAdd(spillN, 1); spillP[k] = ((unsigned)dv.z << 16) | (unsigned)sv.z; }
            if (p3 < CAP) buf[(size_t)dv.w * CAP + p3] = (unsigned short)sv.w;
            else { int k = atomicAdd(spillN, 1); spillP[k] = ((unsigned)dv.w << 16) | (unsigned)sv.w; }
        }
    } else if (b < 6836) {
        int i = (b - 586) * 256 + t;
        float4 v = ((const float4*)x)[i];
        uint2 o;
        o.x = f2bf(v.x) | (f2bf(v.y) << 16);
        o.y = f2bf(v.z) | (f2bf(v.w) << 16);
        ((uint2*)xbf)[i] = o;
    } else {
        int i = (b - 6836) * 256 + t;
        const float* srcs[4] = {wa, wb, wc, wd};
        wbf[i] = (unsigned short)f2bf(srcs[i >> 14][i & 16383]);
    }
}

// ---------------- fused gather + MFMA layer ----------------
// Block = 256 threads = 16 nodes (static grid 3125 — best proven schedule).
// Phase 1 (gather): thread (nl=t>>4, q=t&15) accumulates mean of node node0+nl,
//   cols [8q, 8q+8) in fp32. GATHER_FP8=false: bf16 rows, 256B/row (R7-proven).
//   GATHER_FP8=true: fp8 rows, 128B/row, HW decode via v_cvt_pk_f32_fp8.
//   8-deep unroll -> bf16 LDS tile.
// Phase 2 (MFMA): unchanged R2-proven path; own-row A and W operands bf16.
//   A: lane=(l15,quad) -> row l15, k = quad*8 + kk*32 ; C/D: col=l15, row=quad*4+r.
#define ACC8(vv) do { \
    acc[0] += bf_lo((vv).x); acc[1] += bf_hi((vv).x); \
    acc[2] += bf_lo((vv).y); acc[3] += bf_hi((vv).y); \
    acc[4] += bf_lo((vv).z); acc[5] += bf_hi((vv).z); \
    acc[6] += bf_lo((vv).w); acc[7] += bf_hi((vv).w); } while (0)

#define ACCF8(vv) do { \
    f32x2 p0 = __builtin_amdgcn_cvt_pk_f32_fp8((vv).x, false); \
    f32x2 p1 = __builtin_amdgcn_cvt_pk_f32_fp8((vv).x, true);  \
    f32x2 p2 = __builtin_amdgcn_cvt_pk_f32_fp8((vv).y, false); \
    f32x2 p3 = __builtin_amdgcn_cvt_pk_f32_fp8((vv).y, true);  \
    acc[0] += p0.x; acc[1] += p0.y; acc[2] += p1.x; acc[3] += p1.y; \
    acc[4] += p2.x; acc[5] += p2.y; acc[6] += p3.x; acc[7] += p3.y; } while (0)

template <bool RELU, bool OUT_BF16, bool WRITE_FP8, bool GATHER_FP8>
__global__ void __launch_bounds__(256) k_gather_layer(
    const int* __restrict__ cnt, const unsigned short* __restrict__ buf,
    const int* __restrict__ spillN, const unsigned int* __restrict__ spillP,
    const unsigned char* __restrict__ X8,      // fp8 rows (used iff GATHER_FP8)
    const unsigned short* __restrict__ Xbf,    // bf16 rows: gather (iff !GATHER_FP8), own-row A, spill
    const unsigned short* __restrict__ Wlbf, const float* __restrict__ bias,
    const unsigned short* __restrict__ Wrbf, void* __restrict__ outp,
    unsigned char* __restrict__ out8) {
    __shared__ unsigned short tile[16][136];   // 272 B row stride (16B-mult)

    const int t = threadIdx.x;
    const int node0 = blockIdx.x * 16;         // grid 3125 -> exact

    // ---- phase 1: gather mean ----
    {
        const int nl = t >> 4, q = t & 15;
        const int node = node0 + nl;
        const int deg = cnt[node];
        const int m = deg < CAP ? deg : CAP;
        const unsigned short* __restrict__ nb = buf + (size_t)node * CAP;
        float acc[8] = {0.f, 0.f, 0.f, 0.f, 0.f, 0.f, 0.f, 0.f};
        int e = 0;
        if (GATHER_FP8) {
            for (; e + 8 <= m; e += 8) {
                uint2 v[8];
#pragma unroll
                for (int u = 0; u < 8; ++u)
                    v[u] = *(const uint2*)(X8 + (size_t)nb[e + u] * D + q * 8);
#pragma unroll
                for (int u = 0; u < 8; ++u) ACCF8(v[u]);
            }
            for (; e + 4 <= m; e += 4) {
                uint2 v[4];
#pragma unroll
                for (int u = 0; u < 4; ++u)
                    v[u] = *(const uint2*)(X8 + (size_t)nb[e + u] * D + q * 8);
#pragma unroll
                for (int u = 0; u < 4; ++u) ACCF8(v[u]);
            }
            for (; e < m; ++e) {
                uint2 v = *(const uint2*)(X8 + (size_t)nb[e] * D + q * 8);
                ACCF8(v);
            }
        } else {
            for (; e + 8 <= m; e += 8) {
                uint4 v[8];
#pragma unroll
                for (int u = 0; u < 8; ++u)
                    v[u] = *(const uint4*)(Xbf + (size_t)nb[e + u] * D + q * 8);
#pragma unroll
                for (int u = 0; u < 8; ++u) ACC8(v[u]);
            }
            for (; e + 4 <= m; e += 4) {
                uint4 v[4];
#pragma unroll
                for (int u = 0; u < 4; ++u)
                    v[u] = *(const uint4*)(Xbf + (size_t)nb[e + u] * D + q * 8);
#pragma unroll
                for (int u = 0; u < 4; ++u) ACC8(v[u]);
            }
            for (; e < m; ++e) {
                uint4 v = *(const uint4*)(Xbf + (size_t)nb[e] * D + q * 8);
                ACC8(v);
            }
        }
        if (deg > CAP) {                       // correctness path (bf16 rows); cheap, rarely taken
            int sn = *spillN;
            for (int k = 0; k < sn; ++k) {
                unsigned int p = spillP[k];
                if ((int)(p >> 16) == node) {
                    uint4 v = *(const uint4*)(Xbf + (size_t)(p & 0xFFFFu) * D + q * 8);
                    ACC8(v);
                }
            }
        }
        float inv = (deg > 0) ? 1.0f / (float)deg : 0.0f;
        uint4 o;
        o.x = f2bf(acc[0] * inv) | (f2bf(acc[1] * inv) << 16);
        o.y = f2bf(acc[2] * inv) | (f2bf(acc[3] * inv) << 16);
        o.z = f2bf(acc[4] * inv) | (f2bf(acc[5] * inv) << 16);
        o.w = f2bf(acc[6] * inv) | (f2bf(acc[7] * inv) << 16);
        *(uint4*)(&tile[nl][q * 8]) = o;
    }
    __syncthreads();

    // ---- phase 2: MFMA ----
    const int lane = t & 63;
    const int wv = t >> 6;                 // wave id 0..3 -> feats [32wv, 32wv+32)
    const int l15 = lane & 15;
    const int quad = lane >> 4;

    floatx4 c0 = (floatx4)(0.f), c1 = (floatx4)(0.f);
    const int nf0 = wv * 2, nf1 = wv * 2 + 1;

    const unsigned short* mrow = &tile[l15][quad * 8];
    const unsigned short* arowX = Xbf + (size_t)(node0 + l15) * D + quad * 8;

#pragma unroll
    for (int kk = 0; kk < 4; ++kk) {
        bf16x8 a = *(const bf16x8*)(mrow + kk * 32);
        bf16x8 b0 = *(const bf16x8*)(Wlbf + (size_t)(nf0 * 16 + l15) * D + kk * 32 + quad * 8);
        bf16x8 b1 = *(const bf16x8*)(Wlbf + (size_t)(nf1 * 16 + l15) * D + kk * 32 + quad * 8);
        c0 = __builtin_amdgcn_mfma_f32_16x16x32_bf16(a, b0, c0, 0, 0, 0);
        c1 = __builtin_amdgcn_mfma_f32_16x16x32_bf16(a, b1, c1, 0, 0, 0);
    }
#pragma unroll
    for (int kk = 0; kk < 4; ++kk) {
        bf16x8 a = *(const bf16x8*)(arowX + kk * 32);
        bf16x8 b0 = *(const bf16x8*)(Wrbf + (size_t)(nf0 * 16 + l15) * D + kk * 32 + quad * 8);
        bf16x8 b1 = *(const bf16x8*)(Wrbf + (size_t)(nf1 * 16 + l15) * D + kk * 32 + quad * 8);
        c0 = __builtin_amdgcn_mfma_f32_16x16x32_bf16(a, b0, c0, 0, 0, 0);
        c1 = __builtin_amdgcn_mfma_f32_16x16x32_bf16(a, b1, c1, 0, 0, 0);
    }

#pragma unroll
    for (int j = 0; j < 2; ++j) {
        floatx4 c = j ? c1 : c0;
        int f = (wv * 2 + j) * 16 + l15;
        float bv = bias[f];
#pragma unroll
        for (int r = 0; r < 4; ++r) {
            float v = c[r] + bv;
            if (RELU) v = v > 0.f ? v : 0.2f * v;
            int node = node0 + quad * 4 + r;
            if (OUT_BF16)
                ((unsigned short*)outp)[(size_t)node * D + f] = (unsigned short)f2bf(v);
            else
                ((float*)outp)[(size_t)node * D + f] = v;
            if (WRITE_FP8) {
                int pk = __builtin_amdgcn_cvt_pk_fp8_f32(v, v, 0, false);
                out8[(size_t)node * D + f] = (unsigned char)(pk & 0xFF);
            }
        }
    }
}

// ---------------- host launch ----------------

extern "C" void kernel_launch(void* const* d_in, const int* in_sizes, int n_in,
                              void* d_out, int out_size, void* d_ws, size_t ws_size,
                              hipStream_t stream) {
    (void)in_sizes; (void)n_in; (void)out_size; (void)ws_size;

    const float* x   = (const float*)d_in[0];
    const int*   ei  = (const int*)d_in[1];
    const float* W1l = (const float*)d_in[2];
    const float* b1  = (const float*)d_in[3];
    const float* W1r = (const float*)d_in[4];
    const float* W2l = (const float*)d_in[5];
    const float* b2  = (const float*)d_in[6];
    const float* W2r = (const float*)d_in[7];

    const int* src = ei;
    const int* dst = ei + N_EDGES;

    char* ws = (char*)d_ws;
    int* cnt              = (int*)(ws + 0);                      // 200,000 B
    int* spillN           = (int*)(ws + 200000);                 // 4 B (zeroed with cnt)
    unsigned int* spillP  = (unsigned int*)(ws + 200064);        // 2,400,000 B packed (dst<<16|src)
    unsigned short* buf   = (unsigned short*)(ws + 2600064);     // 3,200,000 B (50000*32 u16)
    unsigned short* wbf   = (unsigned short*)(ws + 5800064);     // 131,072 B
    unsigned short* hbf   = (unsigned short*)(ws + 5931136);     // 12,800,000 B
    unsigned char* h8     = (unsigned char*)(ws + 18731136);     // 6,400,000 B  (ends 25.13 MB <= proven 28.33 MB)

    // d_out (25.6 MB) holds ONLY xbf (R7/R10-proven pattern): layer 2 never reads
    // x, so the final fp32 output write may clobber it.
    unsigned short* xbf = (unsigned short*)d_out;
    float* out = (float*)d_out;

    unsigned short* w1l_bf = wbf;
    unsigned short* w1r_bf = wbf + 16384;
    unsigned short* w2l_bf = wbf + 32768;
    unsigned short* w2r_bf = wbf + 49152;

    hipMemsetAsync(ws, 0, 200064, stream);   // cnt + spillN

    k_prep<<<7092, 256, 0, stream>>>(x, xbf, W1l, W1r, W2l, W2r, wbf,
                                     src, dst, cnt, buf, spillN, spillP);

    // layer 1: bf16 gather from xbf (R7-proven), writes hbf (bf16) + h8 (fp8)
    k_gather_layer<true, true, true, false><<<NTILES, 256, 0, stream>>>(
        cnt, buf, spillN, spillP, nullptr, xbf, w1l_bf, b1, w1r_bf, (void*)hbf, h8);
    // layer 2: fp8 gather from h8 (half the row bytes), bf16 own-row/W
    k_gather_layer<false, false, false, true><<<NTILES, 256, 0, stream>>>(
        cnt, buf, spillN, spillP, h8, hbf, w2l_bf, b2, w2r_bf, (void*)out, nullptr);
}